// Round 7
// baseline (2352.734 us; speedup 1.0000x reference)
//
#include <hip/hip_runtime.h>
#include <hip/hip_bf16.h>
#include <hip/hip_fp16.h>

#define DIMK 1024
#define SEQ  2048
#define BATCH 4
#define NTOK (BATCH*SEQ)                    // 8192
#define PROJ_ELEMS ((size_t)NTOK*DIMK)      // 8388608
#define LD 2048                             // leading dim (elements) of every GEMM operand

typedef unsigned short ushort_t;
typedef __attribute__((ext_vector_type(8))) short short8;   // 8 x bf16 (4 VGPRs)
typedef __attribute__((ext_vector_type(4))) float float4v;  // MFMA accumulator

#define MFMA_BF16 __builtin_amdgcn_mfma_f32_16x16x32_bf16

__device__ __forceinline__ unsigned short f2bf(float f) {
    union { float f; unsigned int i; } x; x.f = f;
    unsigned int r = x.i + 0x7fffu + ((x.i >> 16) & 1u);    // RNE
    return (unsigned short)(r >> 16);
}

// global -> LDS direct copy, 16 B per lane. LDS dest is wave-uniform base;
// HW scatters lane i to base + i*16. Source address is per-lane.
__device__ __forceinline__ void gld_lds16(const void* g, void* l) {
    auto gp = reinterpret_cast<const __attribute__((address_space(1))) unsigned int*>(
        reinterpret_cast<uintptr_t>(g));
    auto lp = reinterpret_cast<__attribute__((address_space(3))) unsigned int*>(
        reinterpret_cast<uintptr_t>(l));
    __builtin_amdgcn_global_load_lds(gp, lp, 16, 0, 0);
}

// Stage one pair of 16x32 sub-chunk units (rg0, rg0+1): 2 global_load_lds per
// thread. Source swizzle (verified conflict-free + coalesced): within each
// 16-row unit, row g's 16B chunk c sits at slot (c + g/2) & 3 — a permutation
// inside each 64B line, so staging lanes 4g..4g+3 still cover one aligned
// 64B segment.
__device__ __forceinline__ void stage2(const ushort_t* __restrict__ gbase,
                                       ushort_t* lbase, int kcol,
                                       int rg0, int g, int scol)
{
    gld_lds16(gbase + (size_t)(rg0 * 16 + g) * LD + kcol + scol,
              lbase + rg0 * 512);
    gld_lds16(gbase + (size_t)(rg0 * 16 + 16 + g) * LD + kcol + scol,
              lbase + rg0 * 512 + 512);
}

// ---------------------------------------------------------------------------
// R7 EXPERIMENT (proj only): 256x256 tile, 8 waves, BK=32, 64 KiB LDS ->
// 2 blocks/CU = 16 waves/CU (4/SIMD, two independent barrier convoys).
// R6 falsified 2-blocks-with-4-wave-blocks (6-8 waves/CU: no overlap);
// R0/m97 overlap worked at 12 waves/CU. This isolates wave count while
// keeping the proven 8-wave 128x64-per-wave geometry.
// Per 32-K step: { 12 ds_read (slot s&1) | stage step s+1 (4 gld_lds/thr)
//   | 32 MFMA (setprio) | vmcnt(0) | barrier }  — m97 pattern; the drain
// is covered by the co-resident block's waves.
// LDS: A 2 slots x 8192 elem + B 2 slots x 8192 elem = 64 KiB.
// ---------------------------------------------------------------------------
__device__ __forceinline__ void gemm_core_bk32(
    const ushort_t* __restrict__ Arow,   // A + m0*LD (256-row tile)
    const ushort_t* __restrict__ Brow,   // B + n0*LD (256-row panel)
    int kend,                            // multiple of 32
    ushort_t* Alds, ushort_t* Blds,      // each 2*8192 elements
    float4v acc[8][4], int wid, int lane)
{
    const int g    = lane >> 2;
    const int sx   = lane & 3;
    const int scol = ((sx - (g >> 1)) & 3) * 8;
    const int r16  = lane & 15;
    const int quad = lane >> 4;
    const int roff = r16 * 32 + ((quad + (r16 >> 1)) & 3) * 8;
    const int wm8 = (wid >> 2) * 8;      // A unit base (0 or 8)   [2M x 4N]
    const int wn4 = (wid & 3) * 4;       // B unit base (0,4,8,12)
    const int rg0 = wid * 2;             // staging: 2 units each of A and B
    const int L = kend >> 5;

    auto STAGE = [&](int s) {
        const int sl = (s & 1) * 8192;
        const int kc = s * 32;
        stage2(Arow, Alds + sl, kc, rg0, g, scol);
        stage2(Brow, Blds + sl, kc, rg0, g, scol);
    };

    STAGE(0);
    asm volatile("s_waitcnt vmcnt(0)" ::: "memory");
    __builtin_amdgcn_s_barrier();
    asm volatile("" ::: "memory");

    for (int s = 0; s < L; ++s) {
        const int sl = (s & 1) * 8192;
        short8 af[8], bf[4];
        #pragma unroll
        for (int j = 0; j < 4; ++j)
            bf[j] = *(const short8*)(Blds + sl + (wn4 + j) * 512 + roff);
        #pragma unroll
        for (int i = 0; i < 8; ++i)
            af[i] = *(const short8*)(Alds + sl + (wm8 + i) * 512 + roff);
        if (s + 1 < L) STAGE(s + 1);
        __builtin_amdgcn_s_setprio(1);
        #pragma unroll
        for (int i = 0; i < 8; ++i)
            #pragma unroll
            for (int j = 0; j < 4; ++j)
                acc[i][j] = MFMA_BF16(af[i], bf[j], acc[i][j], 0, 0, 0);
        __builtin_amdgcn_s_setprio(0);
        asm volatile("s_waitcnt vmcnt(0)" ::: "memory");
        __builtin_amdgcn_s_barrier();
        asm volatile("" ::: "memory");
    }
}

// ---------------------------------------------------------------------------
// R4 core (best measured) — used by scores and pv:
// 256x256 tile, 8 waves, BK=64, 128 KiB LDS double-buffer, 4 phases/tile,
// counted vmcnt(4), barriers per phase, compiler-counted lgkm waits.
// ---------------------------------------------------------------------------
__device__ __forceinline__ void gemm_core256(
    const ushort_t* __restrict__ Arow,
    const ushort_t* __restrict__ Brow,
    int kend,                            // multiple of 256
    ushort_t* Alds, ushort_t* Blds,      // 2*16384 elements each
    float4v acc[8][4], int wid, int lane)
{
    const int g    = lane >> 2;
    const int sx   = lane & 3;
    const int scol = ((sx - (g >> 1)) & 3) * 8;
    const int r16  = lane & 15;
    const int quad = lane >> 4;
    const int roff = r16 * 32 + ((quad + (r16 >> 1)) & 3) * 8;
    const int wm8 = (wid >> 2) * 8;
    const int wn4 = (wid & 3) * 4;
    const int rg0 = wid * 2;
    const int NT = kend >> 6;

    stage2(Brow, Blds,        0,  rg0, g, scol);   // B kh0
    stage2(Arow, Alds,        0,  rg0, g, scol);   // A kh0
    stage2(Brow, Blds + 8192, 32, rg0, g, scol);   // B kh1
    stage2(Arow, Alds + 8192, 32, rg0, g, scol);   // A kh1
    asm volatile("s_waitcnt vmcnt(4)" ::: "memory");
    __builtin_amdgcn_s_barrier();

    for (int t = 0; t < NT; ++t) {
        const int d     = (t & 1) << 14;
        const int dn    = d ^ 16384;
        const int knext = (t + 1) << 6;
        const bool pre  = (t + 1 < NT);
        short8 af0[4], af1[4], bf[4];

        // ===== half 0 (kh0): 32 MFMA, stage B+A kh0 of t+1 =====
        #pragma unroll
        for (int j = 0; j < 4; ++j)
            bf[j] = *(const short8*)(Blds + d + (wn4 + j) * 512 + roff);
        #pragma unroll
        for (int i = 0; i < 4; ++i)
            af0[i] = *(const short8*)(Alds + d + (wm8 + i) * 512 + roff);
        #pragma unroll
        for (int i = 0; i < 4; ++i)
            af1[i] = *(const short8*)(Alds + d + (wm8 + 4 + i) * 512 + roff);
        if (pre) {
            stage2(Brow, Blds + dn, knext, rg0, g, scol);
            stage2(Arow, Alds + dn, knext, rg0, g, scol);
        }
        __builtin_amdgcn_s_setprio(1);
        #pragma unroll
        for (int i = 0; i < 4; ++i)
            #pragma unroll
            for (int j = 0; j < 4; ++j)
                acc[i][j] = MFMA_BF16(af0[i], bf[j], acc[i][j], 0, 0, 0);
        #pragma unroll
        for (int i = 0; i < 4; ++i)
            #pragma unroll
            for (int j = 0; j < 4; ++j)
                acc[4 + i][j] = MFMA_BF16(af1[i], bf[j], acc[4 + i][j], 0, 0, 0);
        __builtin_amdgcn_s_setprio(0);
        if (pre) asm volatile("s_waitcnt vmcnt(4)" ::: "memory");
        else     asm volatile("s_waitcnt vmcnt(0)" ::: "memory");
        __builtin_amdgcn_s_barrier();

        // ===== half 1 (kh1): 32 MFMA, stage B+A kh1 of t+1 =====
        #pragma unroll
        for (int j = 0; j < 4; ++j)
            bf[j] = *(const short8*)(Blds + d + 8192 + (wn4 + j) * 512 + roff);
        #pragma unroll
        for (int i = 0; i < 4; ++i)
            af0[i] = *(const short8*)(Alds + d + 8192 + (wm8 + i) * 512 + roff);
        #pragma unroll
        for (int i = 0; i < 4; ++i)
            af1[i] = *(const short8*)(Alds + d + 8192 + (wm8 + 4 + i) * 512 + roff);
        if (pre) {
            stage2(Brow, Blds + dn + 8192, knext + 32, rg0, g, scol);
            stage2(Arow, Alds + dn + 8192, knext + 32, rg0, g, scol);
        }
        __builtin_amdgcn_s_setprio(1);
        #pragma unroll
        for (int i = 0; i < 4; ++i)
            #pragma unroll
            for (int j = 0; j < 4; ++j)
                acc[i][j] = MFMA_BF16(af0[i], bf[j], acc[i][j], 0, 0, 0);
        #pragma unroll
        for (int i = 0; i < 4; ++i)
            #pragma unroll
            for (int j = 0; j < 4; ++j)
                acc[4 + i][j] = MFMA_BF16(af1[i], bf[j], acc[4 + i][j], 0, 0, 0);
        __builtin_amdgcn_s_setprio(0);
        if (pre) asm volatile("s_waitcnt vmcnt(4)" ::: "memory");
        __builtin_amdgcn_s_barrier();
    }
}

// ---------------------------------------------------------------------------
// Merged projection GEMM: [Q|K|V]cat[8192,2048] = Zcat[8192,2048] @ Wall^T,
// Wall = [Wsq;Wsk;Wsv] rows 0..6143. grid (24, 32); BK32 core, 2 blocks/CU.
// ---------------------------------------------------------------------------
__global__ __launch_bounds__(512, 4)
void gemm_proj(const ushort_t* __restrict__ A, const ushort_t* __restrict__ B,
               ushort_t* __restrict__ Cq, ushort_t* __restrict__ Ck,
               ushort_t* __restrict__ Cv)
{
    __shared__ ushort_t smem[32768];           // 64 KiB: A 2x8192 | B 2x8192
    const int tid = threadIdx.x, wid = tid >> 6, lane = tid & 63;
    const int m0 = blockIdx.y * 256;
    const int n0g = blockIdx.x * 256;          // 0..5888
    ushort_t* C = (n0g < 2048) ? Cq : ((n0g < 4096) ? Ck : Cv);
    const int n0 = n0g & 2047;
    float4v acc[8][4] = {};
    gemm_core_bk32(A + (size_t)m0 * LD, B + (size_t)n0g * LD, 2048,
                   smem, smem + 16384, acc, wid, lane);

    const int wm = wid >> 2, wn = wid & 3;
    const int col16 = lane & 15, quad = lane >> 4;
    #pragma unroll
    for (int i = 0; i < 8; ++i)
        #pragma unroll
        for (int j = 0; j < 4; ++j) {
            const int n = n0 + wn * 64 + j * 16 + col16;
            #pragma unroll
            for (int r = 0; r < 4; ++r) {
                const int m = m0 + wm * 128 + i * 16 + quad * 4 + r;
                C[(size_t)m * LD + n] = f2bf(acc[i][j][r]);
            }
        }
}

// ---------------------------------------------------------------------------
// Scores GEMM (causal tiles): S[b][s][t] fp16 = (Qcat@Kcat^T)*scale
// grid (8 t-tiles, 8 s-tiles, 4 batches); skip jt>it.  (R4 core)
// ---------------------------------------------------------------------------
__global__ __launch_bounds__(512, 2)
void gemm_scores(const ushort_t* __restrict__ Q, const ushort_t* __restrict__ K,
                 __half* __restrict__ S)
{
    const int jt = blockIdx.x, it = blockIdx.y, b = blockIdx.z;
    if (jt > it) return;
    __shared__ ushort_t smem[65536];
    const int tid = threadIdx.x, wid = tid >> 6, lane = tid & 63;
    const size_t boff = (size_t)b * SEQ * LD;
    float4v acc[8][4] = {};
    gemm_core256(Q + boff + (size_t)it * 256 * LD, K + boff + (size_t)jt * 256 * LD,
                 2048, smem, smem + 32768, acc, wid, lane);

    const int wm = wid >> 2, wn = wid & 3;
    const int col16 = lane & 15, quad = lane >> 4;
    const float scale = 0.03125f;  // 1024^-0.5
    __half* Sb = S + (size_t)b * SEQ * SEQ;
    #pragma unroll
    for (int i = 0; i < 8; ++i)
        #pragma unroll
        for (int j = 0; j < 4; ++j) {
            const int t = jt * 256 + wn * 64 + j * 16 + col16;
            #pragma unroll
            for (int r = 0; r < 4; ++r) {
                const int s = it * 256 + wm * 128 + i * 16 + quad * 4 + r;
                Sb[(size_t)s * SEQ + t] = __float2half(acc[i][j][r] * scale);
            }
        }
}

// ---------------------------------------------------------------------------
// PV GEMM: out[{r,i}][b][s][d] fp32 = P[b] @ VTstack[b]^T, K extent causal
// (P rows zero-padded to 256 multiples by softmax). grid (8,8,4). (R4 core)
// ---------------------------------------------------------------------------
__global__ __launch_bounds__(512, 2)
void gemm_pv(const ushort_t* __restrict__ P, const ushort_t* __restrict__ VT,
             float* __restrict__ out)
{
    const int nt = blockIdx.x, mt = blockIdx.y, b = blockIdx.z;
    __shared__ ushort_t smem[65536];
    const int tid = threadIdx.x, wid = tid >> 6, lane = tid & 63;
    const int kend = (mt + 1) * 256;
    float4v acc[8][4] = {};
    gemm_core256(P + (size_t)b * SEQ * SEQ + (size_t)mt * 256 * LD,
                 VT + (size_t)b * LD * LD + (size_t)nt * 256 * LD,
                 kend, smem, smem + 32768, acc, wid, lane);

    const int wm = wid >> 2, wn = wid & 3;
    const int col16 = lane & 15, quad = lane >> 4;
    #pragma unroll
    for (int i = 0; i < 8; ++i)
        #pragma unroll
        for (int j = 0; j < 4; ++j) {
            const int n = nt * 256 + wn * 64 + j * 16 + col16;
            float* dst = out + ((n < 1024) ? 0 : PROJ_ELEMS);
            const int d = n & 1023;
            #pragma unroll
            for (int r = 0; r < 4; ++r) {
                const int s = mt * 256 + wm * 128 + i * 16 + quad * 4 + r;
                dst[((size_t)b * SEQ + s) * DIMK + d] = acc[i][j][r];
            }
        }
}

// ---------------------------------------------------------------------------
// Input converts
// ---------------------------------------------------------------------------
__global__ __launch_bounds__(256)
void zcat_kernel(const float* __restrict__ zr, const float* __restrict__ zi,
                 ushort_t* __restrict__ zcat)
{
    const size_t e = ((size_t)blockIdx.x * 256 + threadIdx.x) * 8;
    const size_t tok = e >> 11;
    const int c = (int)(e & 2047);
    const float* src = (c < 1024) ? (zr + tok * 1024 + c) : (zi + tok * 1024 + (c - 1024));
    float4 a = *(const float4*)src;
    float4 b = *(const float4*)(src + 4);
    ushort_t* d = zcat + e;
    d[0]=f2bf(a.x); d[1]=f2bf(a.y); d[2]=f2bf(a.z); d[3]=f2bf(a.w);
    d[4]=f2bf(b.x); d[5]=f2bf(b.y); d[6]=f2bf(b.z); d[7]=f2bf(b.w);
}

// All three Wstacks in one launch. ng in [0,6144): sel = ng>>11 picks q/k/v.
// Wstack[n][c]: n<1024: [wr[n] | -wi[n]] ; n>=1024: [wi[n-1024] | wr[n-1024]]
__global__ __launch_bounds__(256)
void wstack_all(const float* __restrict__ wq_r, const float* __restrict__ wq_i,
                const float* __restrict__ wk_r, const float* __restrict__ wk_i,
                const float* __restrict__ wv_r, const float* __restrict__ wv_i,
                ushort_t* __restrict__ wall)
{
    const size_t e = ((size_t)blockIdx.x * 256 + threadIdx.x) * 8;
    const int ng = (int)(e >> 11);                    // 0..6143
    const int c  = (int)(e & 2047);
    const int sel = ng >> 11;                         // 0=q, 1=k, 2=v
    const float* wr = (sel == 0) ? wq_r : ((sel == 1) ? wk_r : wv_r);
    const float* wi = (sel == 0) ? wq_i : ((sel == 1) ? wk_i : wv_i);
    const int n = ng & 2047;
    const int n1 = n & 1023, c1 = c & 1023;
    const float* src;
    float sgn = 1.f;
    if (n < 1024) {
        if (c < 1024) src = wr + (size_t)n1 * 1024 + c1;
        else        { src = wi + (size_t)n1 * 1024 + c1; sgn = -1.f; }
    } else {
        src = ((c < 1024) ? wi : wr) + (size_t)n1 * 1024 + c1;
    }
    float4 a = *(const float4*)src;
    float4 b = *(const float4*)(src + 4);
    ushort_t* d = wall + e;
    d[0]=f2bf(sgn*a.x); d[1]=f2bf(sgn*a.y); d[2]=f2bf(sgn*a.z); d[3]=f2bf(sgn*a.w);
    d[4]=f2bf(sgn*b.x); d[5]=f2bf(sgn*b.y); d[6]=f2bf(sgn*b.z); d[7]=f2bf(sgn*b.w);
}

// ---------------------------------------------------------------------------
// V transpose per batch: VT[b][c][t] = Vcat[b*SEQ + t][c], 64x64 LDS tiles.
// grid (32 t-tiles, 32 c-tiles, 4 batches)
// ---------------------------------------------------------------------------
__global__ __launch_bounds__(256)
void transpose_v(const ushort_t* __restrict__ vcat, ushort_t* __restrict__ vt)
{
    __shared__ ushort_t tile[64][65];
    const int b = blockIdx.z;
    const int t0 = blockIdx.x * 64, c0 = blockIdx.y * 64;
    const int tid = threadIdx.x;
    const int r = tid >> 4, c4 = (tid & 15) * 4;
    const ushort_t* src = vcat + ((size_t)(b * SEQ + t0)) * LD + c0;
    #pragma unroll
    for (int p = 0; p < 4; ++p) {
        const int row = p * 16 + r;
        ushort4 v = *(const ushort4*)(src + (size_t)row * LD + c4);
        tile[row][c4+0]=v.x; tile[row][c4+1]=v.y; tile[row][c4+2]=v.z; tile[row][c4+3]=v.w;
    }
    __syncthreads();
    ushort_t* dst = vt + ((size_t)b * LD + c0) * LD + t0;
    #pragma unroll
    for (int p = 0; p < 4; ++p) {
        const int crow = p * 16 + r;
        ushort4 v;
        v.x = tile[c4+0][crow]; v.y = tile[c4+1][crow];
        v.z = tile[c4+2][crow]; v.w = tile[c4+3][crow];
        *(ushort4*)(dst + (size_t)crow * LD + c4) = v;
    }
}

// ---------------------------------------------------------------------------
// Causal softmax, register-cached (R7): one global read, one expf, one write.
// Row length n = s+1 <= 2048 -> at most 8 elements per thread (256 thr).
// Writes bf16 P in place, zero-padded to a 256 multiple for PV tiles.
// ---------------------------------------------------------------------------
__global__ __launch_bounds__(256)
void softmax_kernel(__half* __restrict__ sc)
{
    const int row = blockIdx.x;          // b*SEQ + s
    const int s = row & (SEQ - 1);
    __half* x = sc + (size_t)row * SEQ;
    ushort_t* xo = (ushort_t*)x;
    const int n = s + 1;
    const int tid = threadIdx.x, wave = tid >> 6, lane = tid & 63;
    __shared__ float red[4];

    float v[8];
    float m = -1e30f;
    #pragma unroll
    for (int k = 0; k < 8; ++k) {
        const int i = tid + k * 256;
        v[k] = (i < n) ? __half2float(x[i]) : -1e30f;
        m = fmaxf(m, v[k]);
    }
    #pragma unroll
    for (int off = 32; off > 0; off >>= 1) m = fmaxf(m, __shfl_down(m, off, 64));
    if (lane == 0) red[wave] = m;
    __syncthreads();
    m = fmaxf(fmaxf(red[0], red[1]), fmaxf(red[2], red[3]));
    __syncthreads();

    float l = 0.f;
    #pragma unroll
    for (int k = 0; k < 8; ++k) { v[k] = __expf(v[k] - m); l += v[k]; }
    #pragma unroll
    for (int off = 32; off > 0; off >>= 1) l += __shfl_down(l, off, 64);
    if (lane == 0) red[wave] = l;
    __syncthreads();
    const float inv = 1.0f / (red[0] + red[1] + red[2] + red[3]);

    const int npad = min(SEQ, ((s >> 8) + 1) << 8);   // pad to 256 for PV tiles
    #pragma unroll
    for (int k = 0; k < 8; ++k) {
        const int i = tid + k * 256;
        if (i < npad) xo[i] = f2bf((i < n) ? v[k] * inv : 0.f);
    }
}

// ---------------------------------------------------------------------------
extern "C" void kernel_launch(void* const* d_in, const int* in_sizes, int n_in,
                              void* d_out, int out_size, void* d_ws, size_t ws_size,
                              hipStream_t stream)
{
    const float* z_real = (const float*)d_in[0];
    const float* z_imag = (const float*)d_in[1];
    const float* wq_r   = (const float*)d_in[2];
    const float* wq_i   = (const float*)d_in[3];
    const float* wk_r   = (const float*)d_in[4];
    const float* wk_i   = (const float*)d_in[5];
    const float* wv_r   = (const float*)d_in[6];
    const float* wv_i   = (const float*)d_in[7];
    // d_in[8]: causal tril mask, handled analytically.

    // Workspace layout (bytes), lifetimes are disjoint by stream order:
    //   [0,          33554432)  Zcat bf16     -> reused as VT bf16
    //   [33554432,   58720256)  Wstack q/k/v bf16 (contiguous = Wall[6144,2048])
    //   [58720256,   92274688)  Qcat bf16
    //   [92274688,  125829120)  Kcat bf16
    //   [125829120, 159383552)  Vcat bf16     -> reused as scores fp16 / P bf16
    uint8_t* ws = (uint8_t*)d_ws;
    ushort_t* zcat = (ushort_t*)(ws + 0);
    ushort_t* wall = (ushort_t*)(ws + 33554432);
    ushort_t* qcat = (ushort_t*)(ws + 58720256);
    ushort_t* kcat = (ushort_t*)(ws + 92274688);
    ushort_t* vcat = (ushort_t*)(ws + 125829120);
    ushort_t* vt   = (ushort_t*)(ws + 0);
    __half*   sc   = (__half*)(ws + 125829120);
    float*    outp = (float*)d_out;

    zcat_kernel<<<dim3(8192), dim3(256), 0, stream>>>(z_real, z_imag, zcat);
    wstack_all<<<dim3(6144), dim3(256), 0, stream>>>(wq_r, wq_i, wk_r, wk_i,
                                                     wv_r, wv_i, wall);

    gemm_proj<<<dim3(24, 32), dim3(512), 0, stream>>>(zcat, wall, qcat, kcat, vcat);

    transpose_v<<<dim3(32, 32, 4), dim3(256), 0, stream>>>(vcat, vt);
    gemm_scores<<<dim3(8, 8, 4), dim3(512), 0, stream>>>(qcat, kcat, sc);
    softmax_kernel<<<dim3(NTOK), dim3(256), 0, stream>>>(sc);
    gemm_pv<<<dim3(8, 8, 4), dim3(512), 0, stream>>>((ushort_t*)sc, vt, outp);
}